// Round 9
// baseline (60.831 us; speedup 1.0000x reference)
//
#include <hip/hip_runtime.h>
#include <math.h>

// KDE via bf16 hi/lo split folded into K of mfma_f32_16x16x32_bf16.
//   arg = k2l*(dot(e,b) - 0.5|e|^2 - 0.5|b|^2),  k2l = exp(-2 log_bw)*log2(e)
//   eval data prescaled by k2l. Per 16x16 tile:
//     MFMA1: A=[Ah|Al] x B=[Bh|Bh]  -> Ah.Bh + Al.Bh
//     MFMA2: A=[Ah|An] x B=[Bl|Bn]  -> Ah.Bl + (cb+ce norm constants)
//   out += exp2(C).  Norms 3-way bf16 split (residual ~2^-27).
// Round-9 change: HALF the exponentials move off the trans pipe onto the
// VALU via a branchless poly exp2 (clamp/floor/deg-5 FMA/exponent-trick).
// C0-tile -> v_exp_f32 (trans pipe), C1-tile -> poly (VALU pipe).
// A/B discriminator for the "trans pipe ~32cyc/wave64 is the bound" theory.

#define LOG_2PI_F 1.8378770664093453f
#define LOG2E_F   1.4426950408889634f

#define M_PTS 8192
#define N_PTS 16384
#define NCH   64                       // N chunks
#define ROWS_PER_CHUNK (N_PTS / NCH)   // 256
#define TPC (ROWS_PER_CHUNK / 16)      // 16 tiles of 16 base rows
#define TILE_USH 1024                  // 2 planes x 16 rows x 32 bf16
#define CHUNK_USH (TPC * TILE_USH)

typedef __attribute__((ext_vector_type(8))) short bf16x8;
typedef __attribute__((ext_vector_type(4))) float f32x4;

static __device__ __forceinline__ unsigned short f2bf(float x) {
    unsigned u = __float_as_uint(x);
    u += 0x7fffu + ((u >> 16) & 1u);          // RNE
    return (unsigned short)(u >> 16);
}
static __device__ __forceinline__ float bf2f(unsigned short h) {
    return __uint_as_float(((unsigned)h) << 16);
}
static __device__ __forceinline__ uint4 pack8(const unsigned short* a) {
    uint4 u;
    u.x = (unsigned)a[0] | ((unsigned)a[1] << 16);
    u.y = (unsigned)a[2] | ((unsigned)a[3] << 16);
    u.z = (unsigned)a[4] | ((unsigned)a[5] << 16);
    u.w = (unsigned)a[6] | ((unsigned)a[7] << 16);
    return u;
}

// branchless exp2 on the VALU pipe; accumulates acc += 2^x.
// valid for x <= ~1; x < -126 flushes to ~1e-38 (abs err << threshold).
static __device__ __forceinline__ float poly_exp2_acc(float x, float acc) {
    float xc = fmaxf(x, -126.0f);
    float n  = floorf(xc);
    float f  = xc - n;
    // 2^f = 1 + f*(ln2 + f*(ln2^2/2 + f*(ln2^3/6 + f*(ln2^4/24 + f*ln2^5/120))))
    float p = fmaf(f, 0.0013333558f, 0.0096181291f);
    p = fmaf(f, p, 0.0555041087f);
    p = fmaf(f, p, 0.2402265070f);
    p = fmaf(f, p, 0.6931471806f);
    p = fmaf(f, p, 1.0f);
    int ni = (int)n;                          // exact integer, v_cvt_i32_f32
    float s = __int_as_float((ni + 127) << 23);
    return fmaf(p, s, acc);
}

// ---------------------------------------------------------------------------
// pack: base rows -> tiled [hi|lo],[hi|norm] planes; eval rows -> planar h/l/n.
__global__ __launch_bounds__(256) void kde_pack(
        const float* __restrict__ xe, const float* __restrict__ xb,
        const float* __restrict__ log_bw,
        unsigned short* __restrict__ bint,
        unsigned short* __restrict__ eh, unsigned short* __restrict__ el,
        unsigned short* __restrict__ en) {
    int r = blockIdx.x * 256 + threadIdx.x;
    if (r >= N_PTS + M_PTS) return;
    const float k2l = __expf(-2.f * log_bw[0]) * LOG2E_F;

    int is_eval = (r >= N_PTS);
    int rr = is_eval ? (r - N_PTS) : r;
    const float* src = is_eval ? xe : xb;
    float dscale = is_eval ? k2l : 1.0f;       // eval data prescaled

    const float4* row = (const float4*)(src + (size_t)rr * 16);
    unsigned short hs[16], ls[16], ns[16];
    float s = 0.f;
#pragma unroll
    for (int k = 0; k < 4; ++k) {
        float4 v = row[k];
        float c[4] = {v.x, v.y, v.z, v.w};
#pragma unroll
        for (int j = 0; j < 4; ++j) {
            s = fmaf(c[j], c[j], s);
            float d = c[j] * dscale;
            unsigned short h = f2bf(d);
            hs[k*4+j] = h;
            ls[k*4+j] = f2bf(d - bf2f(h));
        }
    }
    // 3-way bf16 split of the scaled norm constant
    float cn = -0.5f * s * k2l;
    unsigned short c0 = f2bf(cn);
    float r1 = cn - bf2f(c0);
    unsigned short c1 = f2bf(r1);
    unsigned short c2 = f2bf(r1 - bf2f(c1));
#pragma unroll
    for (int i = 0; i < 16; ++i) ns[i] = 0;
    if (is_eval) {
        ns[0] = 0x3F80; ns[1] = 0x3F80; ns[2] = 0x3F80;
        ns[3] = c0;     ns[4] = c1;     ns[5] = c2;
    } else {
        ns[0] = c0;     ns[1] = c1;     ns[2] = c2;
        ns[3] = 0x3F80; ns[4] = 0x3F80; ns[5] = 0x3F80;
    }

    if (is_eval) {
        uint4* dh = (uint4*)(eh + (size_t)rr * 16);
        uint4* dl = (uint4*)(el + (size_t)rr * 16);
        uint4* dn = (uint4*)(en + (size_t)rr * 16);
        dh[0] = pack8(hs); dh[1] = pack8(hs + 8);
        dl[0] = pack8(ls); dl[1] = pack8(ls + 8);
        dn[0] = pack8(ns); dn[1] = pack8(ns + 8);
    } else {
        int t = rr >> 4, q = rr & 15;
        unsigned short* p1 = bint + (size_t)t * TILE_USH + q * 32;  // [hi|lo]
        unsigned short* p2 = p1 + 512;                              // [hi|ns]
        uint4* d1 = (uint4*)p1;
        d1[0] = pack8(hs); d1[1] = pack8(hs + 8);
        d1[2] = pack8(ls); d1[3] = pack8(ls + 8);
        uint4* d2 = (uint4*)p2;
        d2[0] = pack8(hs); d2[1] = pack8(hs + 8);
        d2[2] = pack8(ns); d2[3] = pack8(ns + 8);
    }
}

// ---------------------------------------------------------------------------
// main: wave owns TWO 16x16 C tiles (32 eval cols) x one chunk (256 base rows).
// 4 waves/block share the chunk -> L1 reuse. A register double-buffered.
// Tile0 exponentials on trans pipe, tile1 on VALU poly -> both pipes busy.
__global__ __launch_bounds__(256, 8) void kde_mfma2(
        const unsigned short* __restrict__ eh, const unsigned short* __restrict__ el,
        const unsigned short* __restrict__ en,
        const unsigned short* __restrict__ bint,
        float* __restrict__ part) {
    const int lane = threadIdx.x & 63;
    const int widx = threadIdx.x >> 6;
    const int b = blockIdx.x;
    const int chunk = b >> 6;                 // 0..63 (block-uniform)
    const int etp = (b & 63) * 4 + widx;      // 0..255 -> 32 eval cols
    const int cl = lane & 15;
    const int kg = lane >> 4;                 // 0..3 (k-slice)

    const size_t c0i = ((size_t)etp * 32 + cl) * 16;
    const size_t c1i = c0i + 16 * 16;
    const int kgo = (kg & 1) * 8;
    const bf16x8 B1_0 = *(const bf16x8*)(eh + c0i + kgo);
    const bf16x8 B1_1 = *(const bf16x8*)(eh + c1i + kgo);
    const unsigned short* b2src = (kg < 2) ? el : en;
    const bf16x8 B2_0 = *(const bf16x8*)(b2src + c0i + kgo);
    const bf16x8 B2_1 = *(const bf16x8*)(b2src + c1i + kgo);

    const unsigned short* pa =
        bint + (size_t)chunk * CHUNK_USH + (size_t)cl * 32 + (size_t)kg * 8;

    float p0 = 0.f, p1 = 0.f;                 // tile0 (trans pipe), 2 chains
    float q0 = 0.f, q1 = 0.f;                 // tile1 (VALU poly), 2 chains

    bf16x8 A1 = *(const bf16x8*)(pa);
    bf16x8 A2 = *(const bf16x8*)(pa + 512);

#pragma unroll 1
    for (int t = 0; t < TPC - 1; ++t) {
        pa += TILE_USH;
        const bf16x8 A1n = *(const bf16x8*)(pa);
        const bf16x8 A2n = *(const bf16x8*)(pa + 512);

        f32x4 C0 = {0.f, 0.f, 0.f, 0.f};
        C0 = __builtin_amdgcn_mfma_f32_16x16x32_bf16(A1, B1_0, C0, 0, 0, 0);
        C0 = __builtin_amdgcn_mfma_f32_16x16x32_bf16(A2, B2_0, C0, 0, 0, 0);
        f32x4 C1 = {0.f, 0.f, 0.f, 0.f};
        C1 = __builtin_amdgcn_mfma_f32_16x16x32_bf16(A1, B1_1, C1, 0, 0, 0);
        C1 = __builtin_amdgcn_mfma_f32_16x16x32_bf16(A2, B2_1, C1, 0, 0, 0);

        // tile0 -> trans pipe
        p0 += __builtin_amdgcn_exp2f(C0[0]);
        p1 += __builtin_amdgcn_exp2f(C0[1]);
        // tile1 -> VALU poly (interleaved so both pipes fill)
        q0 = poly_exp2_acc(C1[0], q0);
        q1 = poly_exp2_acc(C1[1], q1);
        p0 += __builtin_amdgcn_exp2f(C0[2]);
        p1 += __builtin_amdgcn_exp2f(C0[3]);
        q0 = poly_exp2_acc(C1[2], q0);
        q1 = poly_exp2_acc(C1[3], q1);

        A1 = A1n;
        A2 = A2n;
    }
    {   // peeled last tile
        f32x4 C0 = {0.f, 0.f, 0.f, 0.f};
        C0 = __builtin_amdgcn_mfma_f32_16x16x32_bf16(A1, B1_0, C0, 0, 0, 0);
        C0 = __builtin_amdgcn_mfma_f32_16x16x32_bf16(A2, B2_0, C0, 0, 0, 0);
        f32x4 C1 = {0.f, 0.f, 0.f, 0.f};
        C1 = __builtin_amdgcn_mfma_f32_16x16x32_bf16(A1, B1_1, C1, 0, 0, 0);
        C1 = __builtin_amdgcn_mfma_f32_16x16x32_bf16(A2, B2_1, C1, 0, 0, 0);
        p0 += __builtin_amdgcn_exp2f(C0[0]);
        p1 += __builtin_amdgcn_exp2f(C0[1]);
        q0 = poly_exp2_acc(C1[0], q0);
        q1 = poly_exp2_acc(C1[1], q1);
        p0 += __builtin_amdgcn_exp2f(C0[2]);
        p1 += __builtin_amdgcn_exp2f(C0[3]);
        q0 = poly_exp2_acc(C1[2], q0);
        q1 = poly_exp2_acc(C1[3], q1);
    }

    float s0 = p0 + p1;                       // tile0: eval cols [0,16)
    float s1 = q0 + q1;                       // tile1: eval cols [16,32)
    s0 += __shfl_xor(s0, 16, 64);             // fold 4 kg row-groups
    s0 += __shfl_xor(s0, 32, 64);
    s1 += __shfl_xor(s1, 16, 64);
    s1 += __shfl_xor(s1, 32, 64);
    if (lane < 16) {
        float* p = part + (size_t)chunk * M_PTS + (size_t)etp * 32;
        p[cl]      = s0;
        p[16 + cl] = s1;
    }
}

// ---------------------------------------------------------------------------
__global__ __launch_bounds__(256) void kde_reduce(
        const float* __restrict__ part, const float* __restrict__ log_bw,
        float* __restrict__ out) {
    int m = blockIdx.x * 256 + threadIdx.x;
    if (m >= M_PTS) return;
    float lb = log_bw[0];
    float scale = __expf(-8.f * LOG_2PI_F - lb) / (float)N_PTS;
    float s = 0.f;
#pragma unroll
    for (int c = 0; c < NCH; ++c) s += part[(size_t)c * M_PTS + m];
    out[m] = scale * s;
}

// ---------------------------------------------------------------------------
extern "C" void kernel_launch(void* const* d_in, const int* in_sizes, int n_in,
                              void* d_out, int out_size, void* d_ws, size_t ws_size,
                              hipStream_t stream) {
    const float* xe = (const float*)d_in[0];   // [8192,16]
    const float* xb = (const float*)d_in[1];   // [16384,16]
    const float* lb = (const float*)d_in[2];   // [1]
    float* out = (float*)d_out;                // [8192]

    unsigned short* bint = (unsigned short*)d_ws;            // 1024 tiles * 1024 ush
    unsigned short* eh = bint + (size_t)(N_PTS / 16) * TILE_USH;
    unsigned short* el = eh + (size_t)M_PTS * 16;
    unsigned short* en = el + (size_t)M_PTS * 16;
    float* part = (float*)(en + (size_t)M_PTS * 16);         // NCH*M_PTS floats

    kde_pack<<<(N_PTS + M_PTS) / 256, 256, 0, stream>>>(xe, xb, lb,
                                                        bint, eh, el, en);
    kde_mfma2<<<4096, 256, 0, stream>>>(eh, el, en, bint, part);
    kde_reduce<<<M_PTS / 256, 256, 0, stream>>>(part, lb, out);
}

// Round 10
// 47.866 us; speedup vs baseline: 1.2709x; 1.2709x over previous
//
#include <hip/hip_runtime.h>
#include <math.h>

// KDE via bf16 hi/lo split MFMA + sparsity guard.
//   arg = k2l*(dot(e,b) - 0.5|e|^2 - 0.5|b|^2) in log2 domain.
//   Key fact: typical arg ~ -577; exp2 underflows below -149. Only
//   P~2.4e-4 of pairs are "live". Guard each 4-element C group with
//   __any(max > -110): ~94% of groups skip exp2+add entirely.
//   Dropped mass <= 16384*2^-110*scale ~ 1e-39 << 5e-18 threshold.
// Base structure = round-6-verified: 32x32x16 MFMA, 3-way norm split,
// tile-interleaved base planes (one vaddr + imm offsets), unroll 1.

#define LOG_2PI_F 1.8378770664093453f
#define LOG2E_F   1.4426950408889634f
#define TH_SKIP   -110.0f

#define M_PTS 8192
#define N_PTS 16384
#define NCH   64                       // N chunks
#define ROWS_PER_CHUNK (N_PTS / NCH)   // 256
#define TPC (ROWS_PER_CHUNK / 32)      // 8 tiles per chunk
#define TILE_USH 1536                  // 3 planes x 32 rows x 16 bf16
#define CHUNK_USH (TPC * TILE_USH)

typedef __attribute__((ext_vector_type(8)))  short bf16x8;
typedef __attribute__((ext_vector_type(16))) float f32x16;

static __device__ __forceinline__ unsigned short f2bf(float x) {
    unsigned u = __float_as_uint(x);
    u += 0x7fffu + ((u >> 16) & 1u);          // RNE
    return (unsigned short)(u >> 16);
}
static __device__ __forceinline__ float bf2f(unsigned short h) {
    return __uint_as_float(((unsigned)h) << 16);
}
static __device__ __forceinline__ uint4 pack8(const unsigned short* a) {
    uint4 u;
    u.x = (unsigned)a[0] | ((unsigned)a[1] << 16);
    u.y = (unsigned)a[2] | ((unsigned)a[3] << 16);
    u.z = (unsigned)a[4] | ((unsigned)a[5] << 16);
    u.w = (unsigned)a[6] | ((unsigned)a[7] << 16);
    return u;
}

// ---------------------------------------------------------------------------
// pack: base rows -> tile-interleaved [hi|lo|norm] planes; eval rows planar.
__global__ __launch_bounds__(256) void kde_pack10(
        const float* __restrict__ xe, const float* __restrict__ xb,
        const float* __restrict__ log_bw,
        unsigned short* __restrict__ bint,
        unsigned short* __restrict__ eh, unsigned short* __restrict__ el,
        unsigned short* __restrict__ en) {
    int r = blockIdx.x * 256 + threadIdx.x;
    if (r >= N_PTS + M_PTS) return;
    const float k2l = __expf(-2.f * log_bw[0]) * LOG2E_F;

    int is_eval = (r >= N_PTS);
    int rr = is_eval ? (r - N_PTS) : r;
    const float* src = is_eval ? xe : xb;
    float dscale = is_eval ? k2l : 1.0f;       // eval data prescaled by k2l

    const float4* row = (const float4*)(src + (size_t)rr * 16);
    unsigned short hs[16], ls[16], ns[16];
    float s = 0.f;
#pragma unroll
    for (int k = 0; k < 4; ++k) {
        float4 v = row[k];
        float c[4] = {v.x, v.y, v.z, v.w};
#pragma unroll
        for (int j = 0; j < 4; ++j) {
            s = fmaf(c[j], c[j], s);
            float d = c[j] * dscale;
            unsigned short h = f2bf(d);
            hs[k*4+j] = h;
            ls[k*4+j] = f2bf(d - bf2f(h));
        }
    }
    // 3-way bf16 split of the scaled norm constant (residual ~2^-27)
    float cn = -0.5f * s * k2l;
    unsigned short c0 = f2bf(cn);
    float r1 = cn - bf2f(c0);
    unsigned short c1 = f2bf(r1);
    unsigned short c2 = f2bf(r1 - bf2f(c1));
#pragma unroll
    for (int i = 0; i < 16; ++i) ns[i] = 0;
    if (is_eval) {
        ns[0] = 0x3F80; ns[1] = 0x3F80; ns[2] = 0x3F80;
        ns[3] = c0;     ns[4] = c1;     ns[5] = c2;
    } else {
        ns[0] = c0;     ns[1] = c1;     ns[2] = c2;
        ns[3] = 0x3F80; ns[4] = 0x3F80; ns[5] = 0x3F80;
    }

    if (is_eval) {
        uint4* dh = (uint4*)(eh + (size_t)rr * 16);
        uint4* dl = (uint4*)(el + (size_t)rr * 16);
        uint4* dn = (uint4*)(en + (size_t)rr * 16);
        dh[0] = pack8(hs); dh[1] = pack8(hs + 8);
        dl[0] = pack8(ls); dl[1] = pack8(ls + 8);
        dn[0] = pack8(ns); dn[1] = pack8(ns + 8);
    } else {
        int t = rr >> 5, q = rr & 31;
        unsigned short* base = bint + (size_t)t * TILE_USH + q * 16;
        uint4* dh = (uint4*)(base);
        uint4* dl = (uint4*)(base + 512);
        uint4* dn = (uint4*)(base + 1024);
        dh[0] = pack8(hs); dh[1] = pack8(hs + 8);
        dl[0] = pack8(ls); dl[1] = pack8(ls + 8);
        dn[0] = pack8(ns); dn[1] = pack8(ns + 8);
    }
}

// ---------------------------------------------------------------------------
// main: wave owns ONE 32x32 C tile (32 eval cols) x one chunk (256 base rows).
// 4 waves/block share the chunk -> L1 reuse. Sparsity guard skips ~94% of
// exp2 groups: inner cost becomes MFMA + fmax/cmp only.
__global__ __launch_bounds__(256, 8) void kde_main10(
        const unsigned short* __restrict__ eh, const unsigned short* __restrict__ el,
        const unsigned short* __restrict__ en,
        const unsigned short* __restrict__ bint,
        float* __restrict__ part) {
    const int lane = threadIdx.x & 63;
    const int widx = threadIdx.x >> 6;
    const int b = blockIdx.x;                 // 0..4095
    const int chunk = b >> 6;                 // 0..63 (block-uniform)
    const int etp = (b & 63) * 4 + widx;      // 0..255 -> 32 eval cols
    const int col = lane & 31;
    const int kg  = lane >> 5;

    // eval (B) fragments — resident for whole kernel
    const size_t eoff = ((size_t)etp * 32 + col) * 16 + (size_t)kg * 8;
    const bf16x8 Bh = *(const bf16x8*)(eh + eoff);
    const bf16x8 Bl = *(const bf16x8*)(el + eoff);
    const bf16x8 Bn = *(const bf16x8*)(en + eoff);

    // base (A): one vaddr; planes at +0 / +512 / +1024 ushorts (imm offsets)
    const unsigned short* pa =
        bint + (size_t)chunk * CHUNK_USH + (size_t)col * 16 + (size_t)kg * 8;

    float acc0 = 0.f, acc1 = 0.f;

#pragma unroll 1
    for (int t = 0; t < TPC; ++t) {
        const bf16x8 Ah = *(const bf16x8*)(pa);
        const bf16x8 Al = *(const bf16x8*)(pa + 512);
        const bf16x8 An = *(const bf16x8*)(pa + 1024);
        pa += TILE_USH;

        f32x16 C;
#pragma unroll
        for (int r = 0; r < 16; ++r) C[r] = 0.f;
        C = __builtin_amdgcn_mfma_f32_32x32x16_bf16(Ah, Bh, C, 0, 0, 0);
        C = __builtin_amdgcn_mfma_f32_32x32x16_bf16(Ah, Bl, C, 0, 0, 0);
        C = __builtin_amdgcn_mfma_f32_32x32x16_bf16(Al, Bh, C, 0, 0, 0);
        C = __builtin_amdgcn_mfma_f32_32x32x16_bf16(An, Bn, C, 0, 0, 0);

        // sparsity guard: a 4-group executes exp2 only if ANY lane is live
#pragma unroll
        for (int r = 0; r < 16; r += 4) {
            float g = fmaxf(fmaxf(C[r], C[r+1]), fmaxf(C[r+2], C[r+3]));
            if (__any(g > TH_SKIP)) {
                acc0 += __builtin_amdgcn_exp2f(C[r]);
                acc1 += __builtin_amdgcn_exp2f(C[r+1]);
                acc0 += __builtin_amdgcn_exp2f(C[r+2]);
                acc1 += __builtin_amdgcn_exp2f(C[r+3]);
            }
        }
    }

    float s = acc0 + acc1;
    s += __shfl_xor(s, 32, 64);               // fold the two kg row-groups
    if (lane < 32)
        part[(size_t)chunk * M_PTS + (size_t)etp * 32 + col] = s;
}

// ---------------------------------------------------------------------------
__global__ __launch_bounds__(256) void kde_red10(
        const float* __restrict__ part, const float* __restrict__ log_bw,
        float* __restrict__ out) {
    int m = blockIdx.x * 256 + threadIdx.x;
    if (m >= M_PTS) return;
    float lb = log_bw[0];
    float scale = __expf(-8.f * LOG_2PI_F - lb) / (float)N_PTS;
    float s = 0.f;
#pragma unroll
    for (int c = 0; c < NCH; ++c) s += part[(size_t)c * M_PTS + m];
    out[m] = scale * s;
}

// ---------------------------------------------------------------------------
extern "C" void kernel_launch(void* const* d_in, const int* in_sizes, int n_in,
                              void* d_out, int out_size, void* d_ws, size_t ws_size,
                              hipStream_t stream) {
    const float* xe = (const float*)d_in[0];   // [8192,16]
    const float* xb = (const float*)d_in[1];   // [16384,16]
    const float* lb = (const float*)d_in[2];   // [1]
    float* out = (float*)d_out;                // [8192]

    unsigned short* bint = (unsigned short*)d_ws;             // 512 tiles * 1536
    unsigned short* eh = bint + (size_t)(N_PTS / 32) * TILE_USH;
    unsigned short* el = eh + (size_t)M_PTS * 16;
    unsigned short* en = el + (size_t)M_PTS * 16;
    float* part = (float*)(en + (size_t)M_PTS * 16);          // NCH*M_PTS floats

    kde_pack10<<<(N_PTS + M_PTS) / 256, 256, 0, stream>>>(xe, xb, lb,
                                                          bint, eh, el, en);
    kde_main10<<<4096, 256, 0, stream>>>(eh, el, en, bint, part);
    kde_red10<<<M_PTS / 256, 256, 0, stream>>>(part, lb, out);
}

// Round 12
// 46.125 us; speedup vs baseline: 1.3188x; 1.0377x over previous
//
#include <hip/hip_runtime.h>
#include <math.h>

// KDE, fused single-pass: pack (f32 -> bf16 hi/lo/norm) + MFMA + guarded exp2.
//   arg = k2l*(dot(e,b) - 0.5|e|^2 - 0.5|b|^2),  k2l = exp(-2*log_bw)*log2(e)
//   eval data prescaled by k2l; norms 3-way bf16 split in k-slots 0..5 of a
//   4th "norms" MFMA.  C = Ah*Bh + Ah*Bl + Al*Bh + An*Bn  (full arg in log2).
//   Sparsity: typical arg ~ -577, exp2 underflows < -149; guard 4-groups with
//   __any(max > -110) -> ~94% skipped (dropped mass ~1e-39 << 5e-18 thresh).
// Round-12: same as round-11 (fused pack+MFMA, LDS A-tiles, register B),
// with the stray address-of-temporary line removed (compile fix).

#define LOG_2PI_F 1.8378770664093453f
#define LOG2E_F   1.4426950408889634f
#define TH_SKIP   -110.0f

#define M_PTS 8192
#define N_PTS 16384
#define NCH   64                       // N chunks
#define ROWS_PER_CHUNK (N_PTS / NCH)   // 256
#define TPC (ROWS_PER_CHUNK / 32)      // 8 tiles per chunk

typedef __attribute__((ext_vector_type(8)))  short bf16x8;
typedef __attribute__((ext_vector_type(16))) float f32x16;

static __device__ __forceinline__ unsigned short f2bf(float x) {
    unsigned u = __float_as_uint(x);
    u += 0x7fffu + ((u >> 16) & 1u);          // RNE
    return (unsigned short)(u >> 16);
}
static __device__ __forceinline__ float bf2f(unsigned short h) {
    return __uint_as_float(((unsigned)h) << 16);
}
static __device__ __forceinline__ uint4 pack8(const unsigned short* a) {
    uint4 u;
    u.x = (unsigned)a[0] | ((unsigned)a[1] << 16);
    u.y = (unsigned)a[2] | ((unsigned)a[3] << 16);
    u.z = (unsigned)a[4] | ((unsigned)a[5] << 16);
    u.w = (unsigned)a[6] | ((unsigned)a[7] << 16);
    return u;
}

// ---------------------------------------------------------------------------
// fused: block = 4 waves; block packs chunk (256 base rows) to LDS + each
// wave packs its 32 eval cols to registers; then 8 x (3 LDS reads + 4 MFMA
// + guarded exp2); partials to part[].
__global__ __launch_bounds__(256) void kde_fused12(
        const float* __restrict__ xe, const float* __restrict__ xb,
        const float* __restrict__ log_bw, float* __restrict__ part) {
    __shared__ unsigned short As[TPC][3][32][16];   // 24576 B

    const int tid  = threadIdx.x;
    const int lane = tid & 63;
    const int widx = tid >> 6;
    const int b = blockIdx.x;                 // 0..4095
    const int chunk = b >> 6;                 // 0..63 (block-uniform)
    const int etp = (b & 63) * 4 + widx;      // 0..255 -> 32 eval cols
    const int col = lane & 31;
    const int kg  = lane >> 5;                // 0/1: k-halves

    const float k2l = __expf(-2.f * log_bw[0]) * LOG2E_F;

    // ---- phase 1a: pack base rows (thread tid <-> row tid of the chunk) ----
    {
        const int t = tid >> 5, q = tid & 31;
        const float4* row = (const float4*)(xb + ((size_t)chunk * ROWS_PER_CHUNK + tid) * 16);
        unsigned short hs[16], ls[16], ns[16];
        float s = 0.f;
#pragma unroll
        for (int k = 0; k < 4; ++k) {
            float4 v = row[k];
            float c[4] = {v.x, v.y, v.z, v.w};
#pragma unroll
            for (int j = 0; j < 4; ++j) {
                s = fmaf(c[j], c[j], s);
                unsigned short h = f2bf(c[j]);
                hs[k*4+j] = h;
                ls[k*4+j] = f2bf(c[j] - bf2f(h));
            }
        }
        float cn = -0.5f * s * k2l;           // scaled norm constant
        unsigned short c0 = f2bf(cn);
        float r1 = cn - bf2f(c0);
        unsigned short c1 = f2bf(r1);
        unsigned short c2 = f2bf(r1 - bf2f(c1));
#pragma unroll
        for (int i = 0; i < 16; ++i) ns[i] = 0;
        ns[0] = c0; ns[1] = c1; ns[2] = c2;
        ns[3] = 0x3F80; ns[4] = 0x3F80; ns[5] = 0x3F80;

        uint4* dh = (uint4*)&As[t][0][q][0];
        dh[0] = pack8(hs); dh[1] = pack8(hs + 8);
        uint4* dl = (uint4*)&As[t][1][q][0];
        dl[0] = pack8(ls); dl[1] = pack8(ls + 8);
        uint4* dn = (uint4*)&As[t][2][q][0];
        dn[0] = pack8(ns); dn[1] = pack8(ns + 8);
    }

    // ---- phase 1b: pack this wave's 32 eval cols into B fragments ----
    bf16x8 Bh, Bl, Bn;
    {
        const float4* erow =
            (const float4*)(xe + ((size_t)(etp * 32 + col)) * 16 + (size_t)kg * 8);
        float4 v0 = erow[0], v1 = erow[1];
        float c[8] = {v0.x, v0.y, v0.z, v0.w, v1.x, v1.y, v1.z, v1.w};
        unsigned short hs[8], ls[8];
        float s = 0.f;
#pragma unroll
        for (int j = 0; j < 8; ++j) {
            s = fmaf(c[j], c[j], s);          // raw norm half
            float d = c[j] * k2l;             // eval data prescaled
            unsigned short h = f2bf(d);
            hs[j] = h;
            ls[j] = f2bf(d - bf2f(h));
        }
        s += __shfl_xor(s, 32, 64);           // combine the two k-halves
        float cn = -0.5f * s * k2l;
        unsigned short c0 = f2bf(cn);
        float r1 = cn - bf2f(c0);
        unsigned short c1 = f2bf(r1);
        unsigned short c2 = f2bf(r1 - bf2f(c1));

        uint4 uh = pack8(hs), ul = pack8(ls);
        Bh = *(const bf16x8*)&uh;
        Bl = *(const bf16x8*)&ul;
        unsigned short nsv[8] = {0,0,0,0,0,0,0,0};
        if (kg == 0) {
            nsv[0] = 0x3F80; nsv[1] = 0x3F80; nsv[2] = 0x3F80;
            nsv[3] = c0;     nsv[4] = c1;     nsv[5] = c2;
        }
        uint4 un = pack8(nsv);
        Bn = *(const bf16x8*)&un;
    }

    __syncthreads();

    // ---- phase 2: 8 tiles, A from LDS ----
    float acc0 = 0.f, acc1 = 0.f;

#pragma unroll 1
    for (int t = 0; t < TPC; ++t) {
        const bf16x8 Ah = *(const bf16x8*)&As[t][0][col][kg * 8];
        const bf16x8 Al = *(const bf16x8*)&As[t][1][col][kg * 8];
        const bf16x8 An = *(const bf16x8*)&As[t][2][col][kg * 8];

        f32x16 C;
#pragma unroll
        for (int r = 0; r < 16; ++r) C[r] = 0.f;
        C = __builtin_amdgcn_mfma_f32_32x32x16_bf16(Ah, Bh, C, 0, 0, 0);
        C = __builtin_amdgcn_mfma_f32_32x32x16_bf16(Ah, Bl, C, 0, 0, 0);
        C = __builtin_amdgcn_mfma_f32_32x32x16_bf16(Al, Bh, C, 0, 0, 0);
        C = __builtin_amdgcn_mfma_f32_32x32x16_bf16(An, Bn, C, 0, 0, 0);

        // sparsity guard: 4-group executes exp2 only if ANY lane is live
#pragma unroll
        for (int r = 0; r < 16; r += 4) {
            float g = fmaxf(fmaxf(C[r], C[r+1]), fmaxf(C[r+2], C[r+3]));
            if (__any(g > TH_SKIP)) {
                acc0 += __builtin_amdgcn_exp2f(C[r]);
                acc1 += __builtin_amdgcn_exp2f(C[r+1]);
                acc0 += __builtin_amdgcn_exp2f(C[r+2]);
                acc1 += __builtin_amdgcn_exp2f(C[r+3]);
            }
        }
    }

    float s = acc0 + acc1;
    s += __shfl_xor(s, 32, 64);               // fold the two kg row-groups
    if (lane < 32)
        part[(size_t)chunk * M_PTS + (size_t)etp * 32 + col] = s;
}

// ---------------------------------------------------------------------------
__global__ __launch_bounds__(256) void kde_red12(
        const float* __restrict__ part, const float* __restrict__ log_bw,
        float* __restrict__ out) {
    int m = blockIdx.x * 256 + threadIdx.x;
    if (m >= M_PTS) return;
    float lb = log_bw[0];
    float scale = __expf(-8.f * LOG_2PI_F - lb) / (float)N_PTS;
    float s = 0.f;
#pragma unroll
    for (int c = 0; c < NCH; ++c) s += part[(size_t)c * M_PTS + m];
    out[m] = scale * s;
}

// ---------------------------------------------------------------------------
extern "C" void kernel_launch(void* const* d_in, const int* in_sizes, int n_in,
                              void* d_out, int out_size, void* d_ws, size_t ws_size,
                              hipStream_t stream) {
    const float* xe = (const float*)d_in[0];   // [8192,16]
    const float* xb = (const float*)d_in[1];   // [16384,16]
    const float* lb = (const float*)d_in[2];   // [1]
    float* out = (float*)d_out;                // [8192]

    float* part = (float*)d_ws;                // NCH*M_PTS floats (2 MB)

    kde_fused12<<<4096, 256, 0, stream>>>(xe, xb, lb, part);
    kde_red12<<<M_PTS / 256, 256, 0, stream>>>(part, lb, out);
}

// Round 13
// 46.046 us; speedup vs baseline: 1.3211x; 1.0017x over previous
//
#include <hip/hip_runtime.h>
#include <math.h>

// KDE, fused single-pass: pack (f32 -> bf16 hi/lo/norm) + MFMA + guarded exp2.
//   arg = k2l*(dot(e,b) - 0.5|e|^2 - 0.5|b|^2),  k2l = exp(-2*log_bw)*log2(e)
//   eval data prescaled by k2l; norms 3-way bf16 split in k-slots 0..5 of a
//   4th "norms" MFMA.  C = Ah*Bh + Ah*Bl + Al*Bh + An*Bn  (full arg in log2).
//   Sparsity: guard 4-groups with __any(max > -110) -> ~94% skipped.
// Round-13: break the per-iteration serial dependency chain.
//   * tiles processed in PAIRS: two independent MFMA chains X,Y interleaved
//     (each mfma's C-input ready ~2 issues early instead of 0)
//   * persistent zero accumulator Z (no per-iter C-init movs)
//   * next pair's 6 A-fragments ds_read-prefetched BEFORE the guard block,
//     so LDS latency hides under the guard VALU tail.

#define LOG_2PI_F 1.8378770664093453f
#define LOG2E_F   1.4426950408889634f
#define TH_SKIP   -110.0f

#define M_PTS 8192
#define N_PTS 16384
#define NCH   64                       // N chunks
#define ROWS_PER_CHUNK (N_PTS / NCH)   // 256
#define TPC (ROWS_PER_CHUNK / 32)      // 8 tiles per chunk

typedef __attribute__((ext_vector_type(8)))  short bf16x8;
typedef __attribute__((ext_vector_type(16))) float f32x16;

static __device__ __forceinline__ unsigned short f2bf(float x) {
    unsigned u = __float_as_uint(x);
    u += 0x7fffu + ((u >> 16) & 1u);          // RNE
    return (unsigned short)(u >> 16);
}
static __device__ __forceinline__ float bf2f(unsigned short h) {
    return __uint_as_float(((unsigned)h) << 16);
}
static __device__ __forceinline__ uint4 pack8(const unsigned short* a) {
    uint4 u;
    u.x = (unsigned)a[0] | ((unsigned)a[1] << 16);
    u.y = (unsigned)a[2] | ((unsigned)a[3] << 16);
    u.z = (unsigned)a[4] | ((unsigned)a[5] << 16);
    u.w = (unsigned)a[6] | ((unsigned)a[7] << 16);
    return u;
}

// ---------------------------------------------------------------------------
__global__ __launch_bounds__(256) void kde_fused13(
        const float* __restrict__ xe, const float* __restrict__ xb,
        const float* __restrict__ log_bw, float* __restrict__ part) {
    __shared__ unsigned short As[TPC][3][32][16];   // 24576 B

    const int tid  = threadIdx.x;
    const int lane = tid & 63;
    const int widx = tid >> 6;
    const int b = blockIdx.x;                 // 0..4095
    const int chunk = b >> 6;                 // 0..63 (block-uniform)
    const int etp = (b & 63) * 4 + widx;      // 0..255 -> 32 eval cols
    const int col = lane & 31;
    const int kg  = lane >> 5;                // 0/1: k-halves

    const float k2l = __expf(-2.f * log_bw[0]) * LOG2E_F;

    // ---- phase 1a: pack base rows (thread tid <-> row tid of the chunk) ----
    {
        const int t = tid >> 5, q = tid & 31;
        const float4* row = (const float4*)(xb + ((size_t)chunk * ROWS_PER_CHUNK + tid) * 16);
        unsigned short hs[16], ls[16], ns[16];
        float s = 0.f;
#pragma unroll
        for (int k = 0; k < 4; ++k) {
            float4 v = row[k];
            float c[4] = {v.x, v.y, v.z, v.w};
#pragma unroll
            for (int j = 0; j < 4; ++j) {
                s = fmaf(c[j], c[j], s);
                unsigned short h = f2bf(c[j]);
                hs[k*4+j] = h;
                ls[k*4+j] = f2bf(c[j] - bf2f(h));
            }
        }
        float cn = -0.5f * s * k2l;           // scaled norm constant
        unsigned short c0 = f2bf(cn);
        float r1 = cn - bf2f(c0);
        unsigned short c1 = f2bf(r1);
        unsigned short c2 = f2bf(r1 - bf2f(c1));
#pragma unroll
        for (int i = 0; i < 16; ++i) ns[i] = 0;
        ns[0] = c0; ns[1] = c1; ns[2] = c2;
        ns[3] = 0x3F80; ns[4] = 0x3F80; ns[5] = 0x3F80;

        uint4* dh = (uint4*)&As[t][0][q][0];
        dh[0] = pack8(hs); dh[1] = pack8(hs + 8);
        uint4* dl = (uint4*)&As[t][1][q][0];
        dl[0] = pack8(ls); dl[1] = pack8(ls + 8);
        uint4* dn = (uint4*)&As[t][2][q][0];
        dn[0] = pack8(ns); dn[1] = pack8(ns + 8);
    }

    // ---- phase 1b: pack this wave's 32 eval cols into B fragments ----
    bf16x8 Bh, Bl, Bn;
    {
        const float4* erow =
            (const float4*)(xe + ((size_t)(etp * 32 + col)) * 16 + (size_t)kg * 8);
        float4 v0 = erow[0], v1 = erow[1];
        float c[8] = {v0.x, v0.y, v0.z, v0.w, v1.x, v1.y, v1.z, v1.w};
        unsigned short hs[8], ls[8];
        float s = 0.f;
#pragma unroll
        for (int j = 0; j < 8; ++j) {
            s = fmaf(c[j], c[j], s);          // raw norm half
            float d = c[j] * k2l;             // eval data prescaled
            unsigned short h = f2bf(d);
            hs[j] = h;
            ls[j] = f2bf(d - bf2f(h));
        }
        s += __shfl_xor(s, 32, 64);           // combine the two k-halves
        float cn = -0.5f * s * k2l;
        unsigned short c0 = f2bf(cn);
        float r1 = cn - bf2f(c0);
        unsigned short c1 = f2bf(r1);
        unsigned short c2 = f2bf(r1 - bf2f(c1));

        uint4 uh = pack8(hs), ul = pack8(ls);
        Bh = *(const bf16x8*)&uh;
        Bl = *(const bf16x8*)&ul;
        unsigned short nsv[8] = {0,0,0,0,0,0,0,0};
        if (kg == 0) {
            nsv[0] = 0x3F80; nsv[1] = 0x3F80; nsv[2] = 0x3F80;
            nsv[3] = c0;     nsv[4] = c1;     nsv[5] = c2;
        }
        uint4 un = pack8(nsv);
        Bn = *(const bf16x8*)&un;
    }

    __syncthreads();

    // ---- phase 2: 4 tile-PAIRS, two independent MFMA chains interleaved ----
    f32x16 Z;
#pragma unroll
    for (int r = 0; r < 16; ++r) Z[r] = 0.f;  // persistent zero accumulator

    float acc0 = 0.f, acc1 = 0.f;

    const int ko = kg * 8;
    bf16x8 Ah0 = *(const bf16x8*)&As[0][0][col][ko];
    bf16x8 Al0 = *(const bf16x8*)&As[0][1][col][ko];
    bf16x8 An0 = *(const bf16x8*)&As[0][2][col][ko];
    bf16x8 Ah1 = *(const bf16x8*)&As[1][0][col][ko];
    bf16x8 Al1 = *(const bf16x8*)&As[1][1][col][ko];
    bf16x8 An1 = *(const bf16x8*)&As[1][2][col][ko];

#pragma unroll 1
    for (int p = 0; p < TPC / 2; ++p) {
        f32x16 X = __builtin_amdgcn_mfma_f32_32x32x16_bf16(Ah0, Bh, Z, 0, 0, 0);
        f32x16 Y = __builtin_amdgcn_mfma_f32_32x32x16_bf16(Ah1, Bh, Z, 0, 0, 0);
        X = __builtin_amdgcn_mfma_f32_32x32x16_bf16(Al0, Bh, X, 0, 0, 0);
        Y = __builtin_amdgcn_mfma_f32_32x32x16_bf16(Al1, Bh, Y, 0, 0, 0);
        X = __builtin_amdgcn_mfma_f32_32x32x16_bf16(Ah0, Bl, X, 0, 0, 0);
        Y = __builtin_amdgcn_mfma_f32_32x32x16_bf16(Ah1, Bl, Y, 0, 0, 0);
        X = __builtin_amdgcn_mfma_f32_32x32x16_bf16(An0, Bn, X, 0, 0, 0);
        Y = __builtin_amdgcn_mfma_f32_32x32x16_bf16(An1, Bn, Y, 0, 0, 0);

        if (p < TPC / 2 - 1) {                // prefetch next pair's A frags
            const int t = 2 * p + 2;
            Ah0 = *(const bf16x8*)&As[t][0][col][ko];
            Al0 = *(const bf16x8*)&As[t][1][col][ko];
            An0 = *(const bf16x8*)&As[t][2][col][ko];
            Ah1 = *(const bf16x8*)&As[t + 1][0][col][ko];
            Al1 = *(const bf16x8*)&As[t + 1][1][col][ko];
            An1 = *(const bf16x8*)&As[t + 1][2][col][ko];
        }

        // guards: exp2 only if any lane in the 4-group is live
#pragma unroll
        for (int r = 0; r < 16; r += 4) {
            float g = fmaxf(fmaxf(X[r], X[r+1]), fmaxf(X[r+2], X[r+3]));
            if (__any(g > TH_SKIP)) {
                acc0 += __builtin_amdgcn_exp2f(X[r]);
                acc1 += __builtin_amdgcn_exp2f(X[r+1]);
                acc0 += __builtin_amdgcn_exp2f(X[r+2]);
                acc1 += __builtin_amdgcn_exp2f(X[r+3]);
            }
        }
#pragma unroll
        for (int r = 0; r < 16; r += 4) {
            float g = fmaxf(fmaxf(Y[r], Y[r+1]), fmaxf(Y[r+2], Y[r+3]));
            if (__any(g > TH_SKIP)) {
                acc0 += __builtin_amdgcn_exp2f(Y[r]);
                acc1 += __builtin_amdgcn_exp2f(Y[r+1]);
                acc0 += __builtin_amdgcn_exp2f(Y[r+2]);
                acc1 += __builtin_amdgcn_exp2f(Y[r+3]);
            }
        }
    }

    float s = acc0 + acc1;
    s += __shfl_xor(s, 32, 64);               // fold the two kg row-groups
    if (lane < 32)
        part[(size_t)chunk * M_PTS + (size_t)etp * 32 + col] = s;
}

// ---------------------------------------------------------------------------
__global__ __launch_bounds__(256) void kde_red13(
        const float* __restrict__ part, const float* __restrict__ log_bw,
        float* __restrict__ out) {
    int m = blockIdx.x * 256 + threadIdx.x;
    if (m >= M_PTS) return;
    float lb = log_bw[0];
    float scale = __expf(-8.f * LOG_2PI_F - lb) / (float)N_PTS;
    float s = 0.f;
#pragma unroll
    for (int c = 0; c < NCH; ++c) s += part[(size_t)c * M_PTS + m];
    out[m] = scale * s;
}

// ---------------------------------------------------------------------------
extern "C" void kernel_launch(void* const* d_in, const int* in_sizes, int n_in,
                              void* d_out, int out_size, void* d_ws, size_t ws_size,
                              hipStream_t stream) {
    const float* xe = (const float*)d_in[0];   // [8192,16]
    const float* xb = (const float*)d_in[1];   // [16384,16]
    const float* lb = (const float*)d_in[2];   // [1]
    float* out = (float*)d_out;                // [8192]

    float* part = (float*)d_ws;                // NCH*M_PTS floats (2 MB)

    kde_fused13<<<4096, 256, 0, stream>>>(xe, xb, lb, part);
    kde_red13<<<M_PTS / 256, 256, 0, stream>>>(part, lb, out);
}